// Round 1
// 894.110 us; speedup vs baseline: 1.0377x; 1.0377x over previous
//
#include <hip/hip_runtime.h>

// Problem constants
#define B_    32
#define A_    1024
#define NN_   5
#define P_    (B_*A_)        // 32768 pairs
#define FIN_  128
#define E0_   128
#define E1_   32
#define H_    32
#define NOUT_ 32
#define NACT_ 8
#define NR_   (P_*NN_)       // 163840 y-rows

// Workspace layout (float units)
#define WS_S   0                       // S[P][NN]          163840
#define WS_H   (WS_S + NR_)            // Hfeat[P][32]      1048576
#define WS_WF  (WS_H + P_*E1_)         // Wfold[32][8]      256
#define WS_CF  (WS_WF + 256)           // cfold[8]          8

__device__ __forceinline__ float b2f_lo(unsigned u) { return __uint_as_float(u << 16); }
__device__ __forceinline__ float b2f_hi(unsigned u) { return __uint_as_float(u & 0xffff0000u); }
__device__ __forceinline__ unsigned short f2b(float f) {
    unsigned u = __float_as_uint(f);
    u += 0x7fffu + ((u >> 16) & 1u);   // RNE
    return (unsigned short)(u >> 16);
}

// ---------------------------------------------------------------------------
// Kernel 1 (fused): grid 3073 blocks x 256.
//   bid % 3 != 2  -> y row-sum role (2048 blocks). HBM-bound: streams 671 MB.
//   bid % 3 == 2  -> embedding MLP role (1024 blocks, 32 pairs each).
//   bid == 3072   -> weight folding.
// Interleaved roles (2:1 mod 3) so embed VALU work co-resides with and hides
// under the y-stream from the first dispatch wavefront.
// LDS 58 KB -> 2 blocks/CU; in-flight analysis: 8 waves/CU x ~8 KB outstanding
// float4 loads = 16 MB chip-wide >> 2.4 MB BW*latency product -> HBM saturated.
// ---------------------------------------------------------------------------
__global__ __launch_bounds__(256) void k_main(
    const float* __restrict__ x,   const float* __restrict__ y,
    const float* __restrict__ We0, const float* __restrict__ be0,
    const float* __restrict__ We1, const float* __restrict__ be1,
    const float* __restrict__ W3,  const float* __restrict__ b3,
    const float* __restrict__ W4,  const float* __restrict__ b4,
    const float* __restrict__ Wp,  const float* __restrict__ bp,
    float* __restrict__ ws)
{
    __shared__ unsigned short sWe0[128*128];   // bf16 [k][o]
    __shared__ unsigned short sWe1[128*32];    // bf16 [k][o2]
    __shared__ float          sU[32*132];      // x tile, then h0 tile (padded 132)
    __shared__ float          sBe0[128];
    __shared__ float          sBe1[32];

    const int tid = threadIdx.x;
    const int bid = blockIdx.x;

    if (bid == 3072) {
        // ---- fold weights (fp32 reads) ----
        float* W34 = sU;                       // 1024 floats scratch
        for (int i = tid; i < 1024; i += 256) {
            int d = i >> 5, q = i & 31;
            float acc = 0.f;
            #pragma unroll
            for (int o = 0; o < 32; ++o)
                acc += W3[d*32+o] * W4[o*32+q];
            W34[i] = acc;
        }
        if (tid < 32) {                        // bw4 = b3@W4 + b4
            float acc = b4[tid];
            #pragma unroll
            for (int d = 0; d < 32; ++d) acc += b3[d] * W4[d*32+tid];
            sBe1[tid] = acc;
        }
        __syncthreads();
        {   // Wfold[d][c]
            int d = tid >> 3, c = tid & 7;
            float acc = 0.f;
            #pragma unroll
            for (int q = 0; q < 32; ++q) acc += W34[d*32+q] * Wp[q*8+c];
            ws[WS_WF + tid] = acc;
        }
        if (tid < 8) {                         // cfold[c]
            float acc = bp[tid];
            #pragma unroll
            for (int q = 0; q < 32; ++q) acc += sBe1[q] * Wp[q*8+tid];
            ws[WS_CF + tid] = acc;
        }
        return;
    }

    if ((bid % 3) != 2) {
        // =============== y row-sum role ===============
        // sb in [0,2048): bijective remap of the 2-of-3 blocks
        const int sb   = (bid / 3) * 2 + (bid % 3);
        const int lane = tid & 63;
        const int wid  = sb * 4 + (tid >> 6);
        const float4* yv = (const float4*)y;
        const int row0 = wid * 20;
        #pragma unroll 2
        for (int i = 0; i < 20; ++i) {
            const int row = row0 + i;
            const size_t base = (size_t)row * 256;       // float4 units (1024/4)
            float4 a = yv[base       + lane];
            float4 b = yv[base +  64 + lane];
            float4 c = yv[base + 128 + lane];
            float4 d = yv[base + 192 + lane];
            float s = ((a.x+a.y)+(a.z+a.w)) + ((b.x+b.y)+(b.z+b.w))
                    + ((c.x+c.y)+(c.z+c.w)) + ((d.x+d.y)+(d.z+d.w));
            #pragma unroll
            for (int off = 32; off > 0; off >>= 1) s += __shfl_down(s, off, 64);
            if (lane == 0) ws[WS_S + row] = s;
        }
        return;
    }

    // =============== embedding MLP role ===============
    const int pair0 = (bid / 3) * 32;

    // ---- stage (convert weights fp32 -> bf16; x stays fp32) ----
    {
        const float4* w0v = (const float4*)We0;            // 4096 float4
        for (int i = tid; i < 4096; i += 256) {
            float4 v = w0v[i];
            unsigned lo = (unsigned)f2b(v.x) | ((unsigned)f2b(v.y) << 16);
            unsigned hi = (unsigned)f2b(v.z) | ((unsigned)f2b(v.w) << 16);
            *(uint2*)(sWe0 + i*4) = make_uint2(lo, hi);
        }
        const float4* w1v = (const float4*)We1;            // 1024 float4
        for (int i = tid; i < 1024; i += 256) {
            float4 v = w1v[i];
            unsigned lo = (unsigned)f2b(v.x) | ((unsigned)f2b(v.y) << 16);
            unsigned hi = (unsigned)f2b(v.z) | ((unsigned)f2b(v.w) << 16);
            *(uint2*)(sWe1 + i*4) = make_uint2(lo, hi);
        }
        const float4* xv = (const float4*)x + (size_t)pair0 * 32;  // 1024 float4
        for (int i = tid; i < 1024; i += 256) {
            int row = i >> 5, c4 = (i & 31) << 2;
            *(float4*)(sU + row*132 + c4) = xv[i];
        }
        if (tid < 128) sBe0[tid] = be0[tid];
        if (tid < 32)  sBe1[tid] = be1[tid];
    }
    __syncthreads();

    // ---- layer 1: h0[32][128], microtile 2 rows x 8 cols per thread ----
    const int rg = tid >> 4, cg = tid & 15;
    const int r0 = rg * 2, c0 = cg * 8;
    float acc0[8], acc1[8];
    {
        #pragma unroll
        for (int c = 0; c < 8; ++c) { acc0[c] = sBe0[c0+c]; acc1[c] = acc0[c]; }
        #pragma unroll 4
        for (int k = 0; k < 128; ++k) {
            float xa = sU[(r0+0)*132 + k];
            float xb = sU[(r0+1)*132 + k];
            uint4 wa = *(const uint4*)(sWe0 + k*128 + c0);
            float w0[8];
            w0[0]=b2f_lo(wa.x); w0[1]=b2f_hi(wa.x); w0[2]=b2f_lo(wa.y); w0[3]=b2f_hi(wa.y);
            w0[4]=b2f_lo(wa.z); w0[5]=b2f_hi(wa.z); w0[6]=b2f_lo(wa.w); w0[7]=b2f_hi(wa.w);
            #pragma unroll
            for (int c = 0; c < 8; ++c) {
                acc0[c] = fmaf(xa, w0[c], acc0[c]);
                acc1[c] = fmaf(xb, w0[c], acc1[c]);
            }
        }
    }
    __syncthreads();   // all x reads done; sU now becomes h0
    {
        #pragma unroll
        for (int c = 0; c < 8; c += 4) {
            float4 v0 = make_float4(fmaxf(acc0[c],0.f), fmaxf(acc0[c+1],0.f),
                                    fmaxf(acc0[c+2],0.f), fmaxf(acc0[c+3],0.f));
            float4 v1 = make_float4(fmaxf(acc1[c],0.f), fmaxf(acc1[c+1],0.f),
                                    fmaxf(acc1[c+2],0.f), fmaxf(acc1[c+3],0.f));
            *(float4*)(sU + (r0+0)*132 + c0 + c) = v0;
            *(float4*)(sU + (r0+1)*132 + c0 + c) = v1;
        }
    }
    __syncthreads();

    // ---- layer 2: h[32][32], 1 row x 4 cols per thread ----
    {
        const int rw = tid >> 3;
        const int c4 = (tid & 7) * 4;
        float acc[4];
        #pragma unroll
        for (int i = 0; i < 4; ++i) acc[i] = sBe1[c4+i];
        #pragma unroll 4
        for (int k = 0; k < 128; ++k) {
            float hv = sU[rw*132 + k];
            uint2 w = *(const uint2*)(sWe1 + k*32 + c4);
            acc[0] = fmaf(hv, b2f_lo(w.x), acc[0]);
            acc[1] = fmaf(hv, b2f_hi(w.x), acc[1]);
            acc[2] = fmaf(hv, b2f_lo(w.y), acc[2]);
            acc[3] = fmaf(hv, b2f_hi(w.y), acc[3]);
        }
        float4 v = make_float4(fmaxf(acc[0],0.f), fmaxf(acc[1],0.f),
                               fmaxf(acc[2],0.f), fmaxf(acc[3],0.f));
        *(float4*)(ws + WS_H + (size_t)(pair0 + rw)*32 + c4) = v;
    }
}

// ---------------------------------------------------------------------------
// Kernel 2: attention + output. One thread per (b,j) pair.
// 256 blocks x 128 threads: every CU gets one block (2 waves) -> per-CU LDS
// pipe work halves vs the old 128x256 config (which left half the chip idle).
// ---------------------------------------------------------------------------
__global__ __launch_bounds__(128) void k_att(
    const float* __restrict__ W1, const float* __restrict__ b1,
    const float* __restrict__ W2, const float* __restrict__ b2,
    const float* __restrict__ ws, float* __restrict__ out)
{
    __shared__ float sW1[1024], sW2[1024], sWf[256];
    __shared__ float sB1[32], sB2[32], sCf[8];
    const int tid = threadIdx.x;

    for (int i = tid; i < 1024; i += 128) { sW1[i] = W1[i]; sW2[i] = W2[i]; }
    for (int i = tid; i < 256; i += 128)  sWf[i] = ws[WS_WF + i];
    if (tid < 32) { sB1[tid] = b1[tid]; sB2[tid] = b2[tid]; }
    if (tid < 8)  sCf[tid] = ws[WS_CF + tid];
    __syncthreads();

    const int p = blockIdx.x * 128 + tid;

    float h[32];
    {
        const float4* hv = (const float4*)(ws + WS_H + (size_t)p*32);
        #pragma unroll
        for (int i = 0; i < 8; ++i) {
            float4 v = hv[i];
            h[i*4+0]=v.x; h[i*4+1]=v.y; h[i*4+2]=v.z; h[i*4+3]=v.w;
        }
    }
    float s[5];
    #pragma unroll
    for (int n = 0; n < 5; ++n) s[n] = ws[WS_S + p*5 + n];

    float a[32], u[32];
    #pragma unroll
    for (int og = 0; og < 8; ++og) {
        float a0=sB1[og*4+0], a1=sB1[og*4+1], a2=sB1[og*4+2], a3=sB1[og*4+3];
        float u0=0.f, u1=0.f, u2=0.f, u3=0.f;
        #pragma unroll
        for (int d = 0; d < 32; ++d) {
            float hd = h[d];
            float4 w1v = *(const float4*)(sW1 + d*32 + og*4);
            float4 w2v = *(const float4*)(sW2 + d*32 + og*4);
            a0 = fmaf(hd, w1v.x, a0); a1 = fmaf(hd, w1v.y, a1);
            a2 = fmaf(hd, w1v.z, a2); a3 = fmaf(hd, w1v.w, a3);
            u0 = fmaf(hd, w2v.x, u0); u1 = fmaf(hd, w2v.y, u1);
            u2 = fmaf(hd, w2v.z, u2); u3 = fmaf(hd, w2v.w, u3);
        }
        a[og*4+0]=fmaxf(a0,0.f); a[og*4+1]=fmaxf(a1,0.f);
        a[og*4+2]=fmaxf(a2,0.f); a[og*4+3]=fmaxf(a3,0.f);
        u[og*4+0]=u0; u[og*4+1]=u1; u[og*4+2]=u2; u[og*4+3]=u3;
    }

    float sc[5];
    #pragma unroll
    for (int n = 0; n < 5; ++n) {
        float sn = s[n], acc = 0.f;
        #pragma unroll
        for (int d = 0; d < 32; ++d) {
            float r = fmaf(sn, u[d], sB2[d]);
            r = fmaxf(r, 0.f);
            acc = fmaf(a[d], r, acc);
        }
        sc[n] = acc;
    }
    float m = sc[0];
    #pragma unroll
    for (int n = 1; n < 5; ++n) m = fmaxf(m, sc[n]);
    float e[5], den = 0.f;
    #pragma unroll
    for (int n = 0; n < 5; ++n) { e[n] = __expf(sc[n]-m); den += e[n]; }
    float inv = 1.f / den;
    float att[5], t = 0.f;
    #pragma unroll
    for (int n = 0; n < 5; ++n) { att[n] = e[n]*inv; t = fmaf(att[n], s[n], t); }

    float g[8];
    #pragma unroll
    for (int cg = 0; cg < 2; ++cg) {
        float g0=0.f, g1=0.f, g2=0.f, g3=0.f;
        #pragma unroll
        for (int d = 0; d < 32; ++d) {
            float hd = h[d];
            float4 w = *(const float4*)(sWf + d*8 + cg*4);
            g0 = fmaf(hd, w.x, g0); g1 = fmaf(hd, w.y, g1);
            g2 = fmaf(hd, w.z, g2); g3 = fmaf(hd, w.w, g3);
        }
        g[cg*4+0]=g0; g[cg*4+1]=g1; g[cg*4+2]=g2; g[cg*4+3]=g3;
    }

    // logits: 8 fp32, two float4 stores
    float4 lo = make_float4(fmaf(t, g[0], sCf[0]), fmaf(t, g[1], sCf[1]),
                            fmaf(t, g[2], sCf[2]), fmaf(t, g[3], sCf[3]));
    float4 hi = make_float4(fmaf(t, g[4], sCf[4]), fmaf(t, g[5], sCf[5]),
                            fmaf(t, g[6], sCf[6]), fmaf(t, g[7], sCf[7]));
    float4* op = (float4*)(out + (size_t)p*8);
    op[0] = lo;
    op[1] = hi;

    // att_record (fp32)
    float* ao = out + (size_t)P_*8 + (size_t)p*5;
    #pragma unroll
    for (int n = 0; n < 5; ++n) ao[n] = att[n];
}

// ---------------------------------------------------------------------------
extern "C" void kernel_launch(void* const* d_in, const int* in_sizes, int n_in,
                              void* d_out, int out_size, void* d_ws, size_t ws_size,
                              hipStream_t stream)
{
    const float* x   = (const float*)d_in[0];
    const float* y   = (const float*)d_in[1];
    const float* We0 = (const float*)d_in[2];
    const float* be0 = (const float*)d_in[3];
    const float* We1 = (const float*)d_in[4];
    const float* be1 = (const float*)d_in[5];
    const float* W1  = (const float*)d_in[6];
    const float* b1  = (const float*)d_in[7];
    const float* W2  = (const float*)d_in[8];
    const float* b2  = (const float*)d_in[9];
    const float* W3  = (const float*)d_in[10];
    const float* b3  = (const float*)d_in[11];
    const float* W4  = (const float*)d_in[12];
    const float* b4  = (const float*)d_in[13];
    const float* Wp  = (const float*)d_in[14];
    const float* bp  = (const float*)d_in[15];
    float* ws = (float*)d_ws;
    float* out = (float*)d_out;

    hipLaunchKernelGGL(k_main, dim3(3073), dim3(256), 0, stream,
                       x, y, We0, be0, We1, be1, W3, b3, W4, b4, Wp, bp, ws);
    hipLaunchKernelGGL(k_att, dim3(256), dim3(128), 0, stream,
                       W1, b1, W2, b2, ws, out);
}